// Round 8
// baseline (205.276 us; speedup 1.0000x reference)
//
#include <hip/hip_runtime.h>
#include <hip/hip_bf16.h>

// Problem constants
#define B 2
#define C 512
#define H 8
#define D 64
#define S 4096           // 64*64 tokens
#define O3 1536          // 3*C
#define E2 0.18033688011112042f   // SCALE * log2(e),  SCALE = D^-0.5 = 0.125
#define THR_RAW 64.0f    // defer-max threshold: 8 nats / SCALE

// Workspace layout (ushort offsets; total 22,020,096 ushorts = 44 MB):
//   xT : bf16 [B][S][C]    @ XT_OFF   (x transposed, k-contiguous)
//   wq : bf16 [O3][C]      @ WQ_OFF
//   wo : bf16 [C][C]       @ WO_OFF
//   q  : bf16 [B][H][S][D] @ Q_OFF
//   k  : bf16 [B][H][S][D] @ K_OFF
//   v  : bf16 [B][H][D][S] @ V_OFF    (transposed: d-major)
//   ao : bf16 [B][S][C]    @ AO_OFF   (attention out, channel-contiguous)
#define XT_OFF 0ull
#define WQ_OFF 4194304ull
#define WO_OFF 4980736ull
#define Q_OFF  5242880ull
#define K_OFF  9437184ull
#define V_OFF  13631488ull
#define AO_OFF 17825792ull

typedef __attribute__((ext_vector_type(8))) short bf16x8;
typedef __attribute__((ext_vector_type(4))) float f32x4;

__device__ __forceinline__ ushort f2bf(float f) {
    __hip_bfloat16 h = __float2bfloat16(f);
    return *reinterpret_cast<ushort*>(&h);
}

__device__ __forceinline__ unsigned pack2bf(float lo, float hi) {
    __hip_bfloat162 h = __float22bfloat162_rn(float2{lo, hi});   // x=lo (low 16)
    return *reinterpret_cast<unsigned*>(&h);
}

// ---------------------------------------------------------------------------
// Prep 1: transpose x [b][c][s] fp32 -> xT [b][s][c] bf16 via LDS tile.
// ---------------------------------------------------------------------------
__global__ __launch_bounds__(256) void transpose_x(const float* __restrict__ x,
                                                   ushort* __restrict__ xT) {
    const int s0 = blockIdx.x * 64, c0 = blockIdx.y * 64, b = blockIdx.z;
    const int tid = threadIdx.x;
    __shared__ float T[64][68];

    const float* xb = x + (size_t)b * C * S;
    #pragma unroll
    for (int i = 0; i < 4; ++i) {
        int idx = tid + i * 256;
        int row = idx >> 4, sv = idx & 15;
        *(float4*)&T[row][sv * 4] =
            *(const float4*)&xb[(size_t)(c0 + row) * S + s0 + sv * 4];
    }
    __syncthreads();
    #pragma unroll
    for (int i = 0; i < 2; ++i) {
        int idx = tid + i * 256;
        int orow = idx >> 3, och = idx & 7;
        ushort tmp[8];
        #pragma unroll
        for (int j = 0; j < 8; ++j) tmp[j] = f2bf(T[och * 8 + j][orow]);
        ushort* dst = &xT[((size_t)b * S + s0 + orow) * C + c0 + och * 8];
        *(ushort4*)&dst[0] = *(ushort4*)&tmp[0];
        *(ushort4*)&dst[4] = *(ushort4*)&tmp[4];
    }
}

// ---------------------------------------------------------------------------
// Prep 2: fp32 -> bf16 elementwise (weights).
// ---------------------------------------------------------------------------
__global__ __launch_bounds__(256) void conv_bf16(const float* __restrict__ src,
                                                 ushort* __restrict__ dst, int n4) {
    int idx = blockIdx.x * 256 + threadIdx.x;
    if (idx < n4) {
        float4 v = *(const float4*)&src[(size_t)idx * 4];
        ushort4 o = {f2bf(v.x), f2bf(v.y), f2bf(v.z), f2bf(v.w)};
        *(ushort4*)&dst[(size_t)idx * 4] = o;
    }
}

// ---------------------------------------------------------------------------
// Kernel: QKV projection, bf16 MFMA (unchanged from R4).
// ---------------------------------------------------------------------------
__global__ __launch_bounds__(256) void qkv_mfma(const ushort* __restrict__ xT,
                                                const ushort* __restrict__ wq,
                                                ushort* __restrict__ ws) {
    const int m0 = blockIdx.x * 128;
    const int o0 = blockIdx.y * 128;
    const int b  = blockIdx.z;
    const int tid = threadIdx.x;
    const int w = tid >> 6, l = tid & 63;
    const int l15 = l & 15, l4 = l >> 4;
    const int wr = w >> 1, wc = w & 1;

    __shared__ __align__(16) ushort At[128][72];
    __shared__ __align__(16) ushort Bt[128][72];

    const ushort* Ag = xT + ((size_t)b * S + m0) * C;
    const ushort* Bg = wq + (size_t)o0 * C;

    f32x4 acc[4][4];
    #pragma unroll
    for (int i = 0; i < 4; ++i)
        #pragma unroll
        for (int j = 0; j < 4; ++j) acc[i][j] = (f32x4){0.f, 0.f, 0.f, 0.f};

    for (int k0 = 0; k0 < C; k0 += 64) {
        if (k0) __syncthreads();
        #pragma unroll
        for (int i = 0; i < 4; ++i) {
            int idx = tid + i * 256;
            int row = idx >> 3, ch = idx & 7;
            *(bf16x8*)&At[row][ch * 8] =
                *(const bf16x8*)&Ag[(size_t)row * C + k0 + ch * 8];
            *(bf16x8*)&Bt[row][ch * 8] =
                *(const bf16x8*)&Bg[(size_t)row * C + k0 + ch * 8];
        }
        __syncthreads();
        #pragma unroll
        for (int c = 0; c < 2; ++c) {
            bf16x8 af[4], bfr[4];
            #pragma unroll
            for (int i = 0; i < 4; ++i) {
                af[i]  = *(const bf16x8*)&At[wr * 64 + i * 16 + l15][c * 32 + l4 * 8];
                bfr[i] = *(const bf16x8*)&Bt[wc * 64 + i * 16 + l15][c * 32 + l4 * 8];
            }
            #pragma unroll
            for (int i = 0; i < 4; ++i)
                #pragma unroll
                for (int j = 0; j < 4; ++j)
                    acc[i][j] = __builtin_amdgcn_mfma_f32_16x16x32_bf16(
                        af[i], bfr[j], acc[i][j], 0, 0, 0);
        }
    }

    const int t = o0 >> 9;
    #pragma unroll
    for (int j = 0; j < 4; ++j) {
        const int ob = o0 + wc * 64 + j * 16;
        const int h  = (ob & 511) >> 6;
        const int d0 = (ob & 63) + l15;
        if (t < 2) {
            ushort* dst = ws + (t == 0 ? Q_OFF : K_OFF) + (size_t)(b * H + h) * S * D;
            #pragma unroll
            for (int i = 0; i < 4; ++i) {
                #pragma unroll
                for (int r = 0; r < 4; ++r) {
                    int m = m0 + wr * 64 + i * 16 + l4 * 4 + r;
                    dst[(size_t)m * D + d0] = f2bf(acc[i][j][r]);
                }
            }
        } else {
            ushort* dst = ws + V_OFF + (size_t)(b * H + h) * D * S + (size_t)d0 * S;
            #pragma unroll
            for (int i = 0; i < 4; ++i) {
                int m = m0 + wr * 64 + i * 16 + l4 * 4;
                ushort4 pk = {f2bf(acc[i][j][0]), f2bf(acc[i][j][1]),
                              f2bf(acc[i][j][2]), f2bf(acc[i][j][3])};
                *(ushort4*)&dst[m] = pk;
            }
        }
    }
}

// ---------------------------------------------------------------------------
// Kernel: bf16 MFMA flash attention, v5.
// QBLK=128, 4 waves (256 thr) x 32 q-rows (2 sub-tiles of 16); KVBLK=128.
// Each K/V LDS fragment read feeds BOTH q-subtiles' MFMAs -> LDS read
// traffic per score halves vs v4 (the v4 wall). Row-sum via ones-A MFMA
// (kills the serial 32-add chain + epilogue shuffles). Tree max. P packed
// via v_cvt_pk (pack2bf). Defer-max, reg-prefetch staging, setprio.
// ---------------------------------------------------------------------------
__global__ __launch_bounds__(256) void attn_kernel(const ushort* __restrict__ wsb,
                                                   ushort* __restrict__ aob) {
    const int q0 = blockIdx.x * 128;
    const int h  = blockIdx.y;
    const int b  = blockIdx.z;
    const int tid = threadIdx.x;
    const int w   = tid >> 6;
    const int l   = tid & 63;
    const int l15 = l & 15, l4 = l >> 4;

    const size_t bh = (size_t)(b * H + h);
    const ushort* qg = wsb + Q_OFF + bh * S * D;
    const ushort* kg = wsb + K_OFF + bh * S * D;
    const ushort* vg = wsb + V_OFF + bh * D * S;   // [D][S]

    __shared__ __align__(16) ushort Kt[128][72];   // [kv][d]
    __shared__ __align__(16) ushort Vt[64][136];   // [d][t], t = pi-permuted kv

    // Q B-frags: two 16-row sub-tiles per wave
    bf16x8 b_q[2][2];
    #pragma unroll
    for (int sub = 0; sub < 2; ++sub) {
        int row = q0 + w * 32 + sub * 16 + l15;
        b_q[sub][0] = *(const bf16x8*)&qg[(size_t)row * D + l4 * 8];
        b_q[sub][1] = *(const bf16x8*)&qg[(size_t)row * D + 32 + l4 * 8];
    }

    // o_acc[sub][dt][reg] = O^T[d = dt*16+l4*4+reg][q = l15]; o_sum = row-sum
    f32x4 o_acc[2][4], o_sum[2];
    float m_run[2];
    #pragma unroll
    for (int sub = 0; sub < 2; ++sub) {
        #pragma unroll
        for (int dt = 0; dt < 4; ++dt) o_acc[sub][dt] = (f32x4){0.f, 0.f, 0.f, 0.f};
        o_sum[sub] = (f32x4){0.f, 0.f, 0.f, 0.f};
        m_run[sub] = -1e30f;
    }

    const f32x4 zero4 = (f32x4){0.f, 0.f, 0.f, 0.f};
    const short one_bf = (short)0x3F80;
    const bf16x8 ones8 = {one_bf, one_bf, one_bf, one_bf,
                          one_bf, one_bf, one_bf, one_bf};

    // staging maps (256 threads, 128-kv tile)
    const int krow = tid >> 3, kch = tid & 7;        // K: rows krow+32p
    const int vrow = tid >> 4, vtch = tid & 15;      // V: rows vrow+16p
    const int vc = vtch >> 2, vl4 = vtch & 3;

    bf16x8 kst[4];
    ushort4 vst[4][2];

    // prologue: stage tile 0
    #pragma unroll
    for (int p = 0; p < 4; ++p) {
        kst[p] = *(const bf16x8*)&kg[(size_t)(krow + p * 32) * D + kch * 8];
        #pragma unroll
        for (int jj = 0; jj < 2; ++jj)
            vst[p][jj] = *(const ushort4*)&vg[(size_t)(vrow + p * 16) * S +
                                              (2 * vc + jj) * 16 + vl4 * 4];
    }

    const int NT = S / 128;
    for (int kt = 0; kt < NT; ++kt) {
        // write staged tile (compiler inserts vmcnt waits)
        #pragma unroll
        for (int p = 0; p < 4; ++p) {
            *(bf16x8*)&Kt[krow + p * 32][kch * 8] = kst[p];
            #pragma unroll
            for (int jj = 0; jj < 2; ++jj)
                *(ushort4*)&Vt[vrow + p * 16][vtch * 8 + jj * 4] = vst[p][jj];
        }
        __syncthreads();

        // prefetch next tile into regs; hides under compute
        if (kt + 1 < NT) {
            #pragma unroll
            for (int p = 0; p < 4; ++p) {
                kst[p] = *(const bf16x8*)&kg[(size_t)((kt + 1) * 128 + krow + p * 32) * D + kch * 8];
                #pragma unroll
                for (int jj = 0; jj < 2; ++jj)
                    vst[p][jj] = *(const ushort4*)&vg[(size_t)(vrow + p * 16) * S +
                                                      (kt + 1) * 128 + (2 * vc + jj) * 16 + vl4 * 4];
            }
        }

        // ---- S^T = K Q^T, both q-subtiles share each K-frag read ----
        f32x4 s[2][8];
        __builtin_amdgcn_s_setprio(1);
        #pragma unroll
        for (int nt = 0; nt < 8; ++nt) {
            bf16x8 ak0 = *(const bf16x8*)&Kt[nt * 16 + l15][l4 * 8];
            bf16x8 ak1 = *(const bf16x8*)&Kt[nt * 16 + l15][32 + l4 * 8];
            #pragma unroll
            for (int sub = 0; sub < 2; ++sub) {
                f32x4 t = __builtin_amdgcn_mfma_f32_16x16x32_bf16(ak0, b_q[sub][0], zero4, 0, 0, 0);
                s[sub][nt] = __builtin_amdgcn_mfma_f32_16x16x32_bf16(ak1, b_q[sub][1], t, 0, 0, 0);
            }
        }
        __builtin_amdgcn_s_setprio(0);

        // ---- tile max (tree) + cross-l4 combine ----
        float mt[2];
        #pragma unroll
        for (int sub = 0; sub < 2; ++sub) {
            float m4[8];
            #pragma unroll
            for (int nt = 0; nt < 8; ++nt)
                m4[nt] = fmaxf(fmaxf(s[sub][nt][0], s[sub][nt][1]),
                               fmaxf(s[sub][nt][2], s[sub][nt][3]));
            float a = fmaxf(fmaxf(m4[0], m4[1]), fmaxf(m4[2], m4[3]));
            float c = fmaxf(fmaxf(m4[4], m4[5]), fmaxf(m4[6], m4[7]));
            float m0 = fmaxf(a, c);
            m0 = fmaxf(m0, __shfl_xor(m0, 16, 64));
            m0 = fmaxf(m0, __shfl_xor(m0, 32, 64));
            mt[sub] = m0;
        }

        // ---- defer-max rescale ----
        bool ok = (mt[0] <= m_run[0] + THR_RAW) && (mt[1] <= m_run[1] + THR_RAW);
        if (!__all(ok)) {
            #pragma unroll
            for (int sub = 0; sub < 2; ++sub) {
                float mn = fmaxf(m_run[sub], mt[sub]);
                float alpha = __builtin_amdgcn_exp2f((m_run[sub] - mn) * E2);
                m_run[sub] = mn;
                o_sum[sub] *= alpha;
                #pragma unroll
                for (int dt = 0; dt < 4; ++dt) o_acc[sub][dt] *= alpha;
            }
        }

        // ---- P = exp2(S*E2 - msc), pack to bf16 pairs (cvt_pk) ----
        unsigned pw[2][8][2];
        #pragma unroll
        for (int sub = 0; sub < 2; ++sub) {
            float msc = m_run[sub] * E2;
            #pragma unroll
            for (int nt = 0; nt < 8; ++nt) {
                float p0 = __builtin_amdgcn_exp2f(fmaf(s[sub][nt][0], E2, -msc));
                float p1 = __builtin_amdgcn_exp2f(fmaf(s[sub][nt][1], E2, -msc));
                float p2 = __builtin_amdgcn_exp2f(fmaf(s[sub][nt][2], E2, -msc));
                float p3 = __builtin_amdgcn_exp2f(fmaf(s[sub][nt][3], E2, -msc));
                pw[sub][nt][0] = pack2bf(p0, p1);
                pw[sub][nt][1] = pack2bf(p2, p3);
            }
        }

        // ---- O^T += V^T P (shared V-frag reads); row-sum via ones-A MFMA ----
        __builtin_amdgcn_s_setprio(1);
        #pragma unroll
        for (int c = 0; c < 4; ++c) {
            bf16x8 pb[2];
            #pragma unroll
            for (int sub = 0; sub < 2; ++sub) {
                union { unsigned u[4]; bf16x8 v; } pbu;
                pbu.u[0] = pw[sub][2 * c][0];
                pbu.u[1] = pw[sub][2 * c][1];
                pbu.u[2] = pw[sub][2 * c + 1][0];
                pbu.u[3] = pw[sub][2 * c + 1][1];
                pb[sub] = pbu.v;
            }
            #pragma unroll
            for (int dt = 0; dt < 4; ++dt) {
                bf16x8 av = *(const bf16x8*)&Vt[dt * 16 + l15][c * 32 + l4 * 8];
                #pragma unroll
                for (int sub = 0; sub < 2; ++sub)
                    o_acc[sub][dt] = __builtin_amdgcn_mfma_f32_16x16x32_bf16(
                        av, pb[sub], o_acc[sub][dt], 0, 0, 0);
            }
            #pragma unroll
            for (int sub = 0; sub < 2; ++sub)
                o_sum[sub] = __builtin_amdgcn_mfma_f32_16x16x32_bf16(
                    ones8, pb[sub], o_sum[sub], 0, 0, 0);
        }
        __builtin_amdgcn_s_setprio(0);
        __syncthreads();
    }

    // ---- epilogue: l = o_sum (already full row-sum), normalize, store ----
    #pragma unroll
    for (int sub = 0; sub < 2; ++sub) {
        float inv = 1.0f / o_sum[sub][0];
        int row = q0 + w * 32 + sub * 16 + l15;
        #pragma unroll
        for (int dt = 0; dt < 4; ++dt) {
            ushort4 pk = {f2bf(o_acc[sub][dt][0] * inv), f2bf(o_acc[sub][dt][1] * inv),
                          f2bf(o_acc[sub][dt][2] * inv), f2bf(o_acc[sub][dt][3] * inv)};
            *(ushort4*)&aob[((size_t)b * S + row) * C + h * 64 + dt * 16 + l4 * 4] = pk;
        }
    }
}

// ---------------------------------------------------------------------------
// Kernel: output projection, bf16 MFMA, + bias, fp32 out [b][c][s]
// (unchanged from R4).
// ---------------------------------------------------------------------------
__global__ __launch_bounds__(256) void oproj_mfma(const ushort* __restrict__ wo,
                                                  const ushort* __restrict__ aob,
                                                  const float* __restrict__ b_out,
                                                  float* __restrict__ out) {
    const int cc0 = blockIdx.x * 128;
    const int n0  = blockIdx.y * 128;
    const int b   = blockIdx.z;
    const int tid = threadIdx.x;
    const int w = tid >> 6, l = tid & 63;
    const int l15 = l & 15, l4 = l >> 4;
    const int wr = w >> 1, wc = w & 1;

    __shared__ __align__(16) ushort At[128][72];
    __shared__ __align__(16) ushort Bt[128][72];

    const ushort* Ag = wo + (size_t)cc0 * C;
    const ushort* Bg = aob + ((size_t)b * S + n0) * C;

    f32x4 acc[4][4];
    #pragma unroll
    for (int i = 0; i < 4; ++i)
        #pragma unroll
        for (int j = 0; j < 4; ++j) acc[i][j] = (f32x4){0.f, 0.f, 0.f, 0.f};

    for (int k0 = 0; k0 < C; k0 += 64) {
        if (k0) __syncthreads();
        #pragma unroll
        for (int i = 0; i < 4; ++i) {
            int idx = tid + i * 256;
            int row = idx >> 3, ch = idx & 7;
            *(bf16x8*)&At[row][ch * 8] =
                *(const bf16x8*)&Ag[(size_t)row * C + k0 + ch * 8];
            *(bf16x8*)&Bt[row][ch * 8] =
                *(const bf16x8*)&Bg[(size_t)row * C + k0 + ch * 8];
        }
        __syncthreads();
        #pragma unroll
        for (int c = 0; c < 2; ++c) {
            bf16x8 af[4], bfr[4];
            #pragma unroll
            for (int i = 0; i < 4; ++i) {
                af[i]  = *(const bf16x8*)&At[wr * 64 + i * 16 + l15][c * 32 + l4 * 8];
                bfr[i] = *(const bf16x8*)&Bt[wc * 64 + i * 16 + l15][c * 32 + l4 * 8];
            }
            #pragma unroll
            for (int i = 0; i < 4; ++i)
                #pragma unroll
                for (int j = 0; j < 4; ++j)
                    acc[i][j] = __builtin_amdgcn_mfma_f32_16x16x32_bf16(
                        af[i], bfr[j], acc[i][j], 0, 0, 0);
        }
    }

    #pragma unroll
    for (int i = 0; i < 4; ++i) {
        #pragma unroll
        for (int r = 0; r < 4; ++r) {
            int cc = cc0 + wr * 64 + i * 16 + l4 * 4 + r;
            float bias = b_out[cc];
            #pragma unroll
            for (int j = 0; j < 4; ++j) {
                int mm = n0 + wc * 64 + j * 16 + l15;
                out[((size_t)b * C + cc) * S + mm] = acc[i][j][r] + bias;
            }
        }
    }
}

// ---------------------------------------------------------------------------
extern "C" void kernel_launch(void* const* d_in, const int* in_sizes, int n_in,
                              void* d_out, int out_size, void* d_ws, size_t ws_size,
                              hipStream_t stream) {
    (void)in_sizes; (void)n_in; (void)out_size; (void)ws_size;
    const float* x     = (const float*)d_in[0];
    const float* w_qkv = (const float*)d_in[1];
    const float* w_out = (const float*)d_in[2];
    const float* b_out = (const float*)d_in[3];
    float* out = (float*)d_out;
    ushort* wsb = (ushort*)d_ws;    // 44 MB used

    transpose_x<<<dim3(S / 64, C / 64, B), 256, 0, stream>>>(x, wsb + XT_OFF);
    conv_bf16<<<dim3((O3 * C / 4 + 255) / 256), 256, 0, stream>>>(w_qkv, wsb + WQ_OFF, O3 * C / 4);
    conv_bf16<<<dim3((C * C / 4 + 255) / 256), 256, 0, stream>>>(w_out, wsb + WO_OFF, C * C / 4);
    qkv_mfma<<<dim3(S / 128, O3 / 128, B), 256, 0, stream>>>(wsb + XT_OFF, wsb + WQ_OFF, wsb);
    attn_kernel<<<dim3(S / 128, H, B), 256, 0, stream>>>(wsb, wsb + AO_OFF);
    oproj_mfma<<<dim3(C / 128, S / 128, B), 256, 0, stream>>>(wsb + WO_OFF, wsb + AO_OFF, b_out, out);
}